// Round 1
// baseline (219.390 us; speedup 1.0000x reference)
//
#include <hip/hip_runtime.h>

#define EPSF 1e-5f
constexpr int ROWS    = 4194304;           // B
constexpr int THREADS = 256;
constexpr int BLOCKS  = 2048;
constexpr int TOT     = THREADS * BLOCKS;  // 524288 threads, 8 rows each

// tanh(x) = 1 - 2/(exp(2x)+1).  Saturates correctly for |x| large
// (exp->inf => 1, exp->0 => -1).  2 transcendental ops (v_exp, v_rcp).
__device__ __forceinline__ float fast_tanh(float v) {
    float e = __expf(2.0f * v);
    return 1.0f - __fdividef(2.0f, e + 1.0f);
}

#define WARGS const float* __restrict__ W1, const float* __restrict__ b1, \
              const float* __restrict__ W2, const float* __restrict__ b2, \
              const float* __restrict__ W3, const float* __restrict__ b3, \
              const float* __restrict__ W4, const float* __restrict__ b4, \
              const float* __restrict__ W5, const float* __restrict__ b5, \
              const float* __restrict__ W6, const float* __restrict__ b6, \
              const float* __restrict__ Wh, const float* __restrict__ bh
#define WPASS W1,b1,W2,b2,W3,b3,W4,b4,W5,b5,W6,b6,Wh,bh

// Full MLP for one row -> p0 = softmax(logits)[0] = sigmoid(l0 - l1).
__device__ __forceinline__ float mlp_p0(float x0, float x1, WARGS) {
    float h1[8];
#pragma unroll
    for (int j = 0; j < 8; ++j)
        h1[j] = fast_tanh(fmaf(x1, W1[2*j+1], fmaf(x0, W1[2*j], b1[j])));
    float h2[8];
#pragma unroll
    for (int j = 0; j < 8; ++j) {
        float a = b2[j];
#pragma unroll
        for (int k = 0; k < 8; ++k) a = fmaf(h1[k], W2[8*j+k], a);
        h2[j] = fast_tanh(a);
    }
    float h3[6];
#pragma unroll
    for (int j = 0; j < 6; ++j) {
        float a = b3[j];
#pragma unroll
        for (int k = 0; k < 8; ++k) a = fmaf(h2[k], W3[8*j+k], a);
        h3[j] = fast_tanh(a);
    }
    float h4[4];
#pragma unroll
    for (int j = 0; j < 4; ++j) {
        float a = b4[j];
#pragma unroll
        for (int k = 0; k < 6; ++k) a = fmaf(h3[k], W4[6*j+k], a);
        h4[j] = fast_tanh(a);
    }
    float h5[3];
#pragma unroll
    for (int j = 0; j < 3; ++j) {
        float a = b5[j];
#pragma unroll
        for (int k = 0; k < 4; ++k) a = fmaf(h4[k], W5[4*j+k], a);
        h5[j] = fast_tanh(a);
    }
    float h6[3];
#pragma unroll
    for (int j = 0; j < 3; ++j) {
        float a = b6[j];
#pragma unroll
        for (int k = 0; k < 3; ++k) a = fmaf(h5[k], W6[3*j+k], a);
        h6[j] = fast_tanh(a);
    }
    // logits diff: d = h @ (Wh[0]-Wh[1]) + (bh[0]-bh[1]);  p0 = sigmoid(d)
    float d = bh[0] - bh[1];
#pragma unroll
    for (int j = 0; j < 3; ++j) d = fmaf(h6[j], Wh[j] - Wh[3+j], d);
    return __fdividef(1.0f, 1.0f + __expf(-d));
}

// Pass 1: compute p0 per row; optionally store p0; reduce (sum, sumsq) -> acc.
template <bool STORE>
__global__ __launch_bounds__(THREADS) void k1_probs(
    const float* __restrict__ x, WARGS,
    float* __restrict__ p0out, double* __restrict__ acc)
{
    const int t = blockIdx.x * THREADS + threadIdx.x;
    float s = 0.0f, q = 0.0f;
#pragma unroll
    for (int it = 0; it < 4; ++it) {
        const int rp = it * TOT + t;              // float4 of x = rows 2rp, 2rp+1
        float4 xv = reinterpret_cast<const float4*>(x)[rp];
        float pa = mlp_p0(xv.x, xv.y, WPASS);
        float pb = mlp_p0(xv.z, xv.w, WPASS);
        if (STORE)
            reinterpret_cast<float2*>(p0out)[rp] = make_float2(pa, pb);
        s += pa + pb;
        q += fmaf(pa, pa, pb * pb);
    }
    // wave(64) shuffle reduce
#pragma unroll
    for (int off = 32; off > 0; off >>= 1) {
        s += __shfl_down(s, off);
        q += __shfl_down(q, off);
    }
    __shared__ float ls[THREADS / 64], lq[THREADS / 64];
    const int lane = threadIdx.x & 63, wv = threadIdx.x >> 6;
    if (lane == 0) { ls[wv] = s; lq[wv] = q; }
    __syncthreads();
    if (threadIdx.x == 0) {
        float S = ls[0] + ls[1] + ls[2] + ls[3];
        float Q = lq[0] + lq[1] + lq[2] + lq[3];
        atomicAdd(&acc[0], (double)S);
        atomicAdd(&acc[1], (double)Q);
    }
}

// Pass 2 (stored-p0 path): normalize and write [B,2] output.
__global__ __launch_bounds__(THREADS) void k2_norm(
    const float* __restrict__ p0in, const double* __restrict__ acc,
    const float* __restrict__ gamma, const float* __restrict__ beta,
    float* __restrict__ out)
{
    const double S = acc[0], Q = acc[1];
    const double md = S / (double)ROWS;
    const double vard = (Q - S * md) / (double)ROWS;   // E[p^2] - m^2, in double
    const float  m   = (float)md;
    const float  inv = rsqrtf((float)vard + EPSF);
    const float  a0 = inv * gamma[0], a1 = inv * gamma[1];
    const float  c0 = beta[0] - m * a0;   // out0 =  p*a0 + c0
    const float  c1 = beta[1] + m * a1;   // out1 = -p*a1 + c1
    const int t = blockIdx.x * THREADS + threadIdx.x;
#pragma unroll
    for (int it = 0; it < 4; ++it) {
        const int idx = it * TOT + t;                 // float2 p0 = rows 2idx,2idx+1
        float2 p = reinterpret_cast<const float2*>(p0in)[idx];
        float4 o;
        o.x = fmaf( p.x, a0, c0);
        o.y = fmaf(-p.x, a1, c1);
        o.z = fmaf( p.y, a0, c0);
        o.w = fmaf(-p.y, a1, c1);
        reinterpret_cast<float4*>(out)[idx] = o;
    }
}

// Pass 2 (fallback, no workspace for p0): recompute MLP then normalize.
__global__ __launch_bounds__(THREADS) void k2_recompute(
    const float* __restrict__ x, WARGS, const double* __restrict__ acc,
    const float* __restrict__ gamma, const float* __restrict__ beta,
    float* __restrict__ out)
{
    const double S = acc[0], Q = acc[1];
    const double md = S / (double)ROWS;
    const double vard = (Q - S * md) / (double)ROWS;
    const float  m   = (float)md;
    const float  inv = rsqrtf((float)vard + EPSF);
    const float  a0 = inv * gamma[0], a1 = inv * gamma[1];
    const float  c0 = beta[0] - m * a0;
    const float  c1 = beta[1] + m * a1;
    const int t = blockIdx.x * THREADS + threadIdx.x;
#pragma unroll
    for (int it = 0; it < 4; ++it) {
        const int rp = it * TOT + t;
        float4 xv = reinterpret_cast<const float4*>(x)[rp];
        float pa = mlp_p0(xv.x, xv.y, WPASS);
        float pb = mlp_p0(xv.z, xv.w, WPASS);
        float4 o;
        o.x = fmaf( pa, a0, c0);
        o.y = fmaf(-pa, a1, c1);
        o.z = fmaf( pb, a0, c0);
        o.w = fmaf(-pb, a1, c1);
        reinterpret_cast<float4*>(out)[rp] = o;
    }
}

extern "C" void kernel_launch(void* const* d_in, const int* in_sizes, int n_in,
                              void* d_out, int out_size, void* d_ws, size_t ws_size,
                              hipStream_t stream) {
    const float* x  = (const float*)d_in[0];
    const float* W1 = (const float*)d_in[1];
    const float* b1 = (const float*)d_in[2];
    const float* W2 = (const float*)d_in[3];
    const float* b2 = (const float*)d_in[4];
    const float* W3 = (const float*)d_in[5];
    const float* b3 = (const float*)d_in[6];
    const float* W4 = (const float*)d_in[7];
    const float* b4 = (const float*)d_in[8];
    const float* W5 = (const float*)d_in[9];
    const float* b5 = (const float*)d_in[10];
    const float* W6 = (const float*)d_in[11];
    const float* b6 = (const float*)d_in[12];
    const float* Wh = (const float*)d_in[13];
    const float* bh = (const float*)d_in[14];
    const float* gamma = (const float*)d_in[15];
    const float* beta  = (const float*)d_in[16];
    float*  out = (float*)d_out;
    double* acc = (double*)d_ws;
    float*  p0  = (float*)((char*)d_ws + 256);

    // zero the (sum, sumsq) accumulators (ws is poisoned 0xAA before every call)
    hipMemsetAsync(d_ws, 0, 16, stream);

    const size_t need = 256 + (size_t)ROWS * sizeof(float);
    if (ws_size >= need) {
        k1_probs<true><<<BLOCKS, THREADS, 0, stream>>>(x, WPASS, p0, acc);
        k2_norm<<<BLOCKS, THREADS, 0, stream>>>(p0, acc, gamma, beta, out);
    } else {
        k1_probs<false><<<BLOCKS, THREADS, 0, stream>>>(x, WPASS, p0, acc);
        k2_recompute<<<BLOCKS, THREADS, 0, stream>>>(x, WPASS, acc, gamma, beta, out);
    }
}

// Round 2
// 190.600 us; speedup vs baseline: 1.1510x; 1.1510x over previous
//
#include <hip/hip_runtime.h>

#define EPSF 1e-5f
constexpr int   ROWS      = 4194304;            // B
constexpr int   THREADS   = 256;
constexpr int   K1_BLOCKS = 1024;               // 262144 threads, 8 float4 (16 rows) each
constexpr int   K2_BLOCKS = 2048;
constexpr int   K1_TOT    = K1_BLOCKS * THREADS;
constexpr int   K2_TOT    = K2_BLOCKS * THREADS;

// ---- tanh lookup table: value+slope, linear interp, range [-8,8] ----
constexpr int   TBL_N     = 4096;
constexpr float TBL_R     = 8.0f;
constexpr float TBL_STEP  = 2.0f * TBL_R / TBL_N;          // 0.00390625
constexpr float TBL_SCALE = TBL_N / (2.0f * TBL_R);        // 256
constexpr float TBL_BIAS  = TBL_N * 0.5f;                  // 2048
constexpr float TBL_MAXU  = 4095.999f;

// exact-ish tanh for table build: 1 - 2/(exp(2x)+1)
__device__ __forceinline__ float exact_tanh(float v) {
    float e = __expf(2.0f * v);
    return 1.0f - __fdividef(2.0f, e + 1.0f);
}

__global__ __launch_bounds__(THREADS) void k0_build(float2* __restrict__ gtbl) {
    int i = blockIdx.x * THREADS + threadIdx.x;
    if (i < TBL_N) {
        float x0 = -TBL_R + (float)i * TBL_STEP;
        float t0 = exact_tanh(x0);
        float t1 = exact_tanh(x0 + TBL_STEP);
        gtbl[i] = make_float2(t0, t1 - t0);
    }
}

// table tanh: ~7 VALU + 1 ds_read_b64
__device__ __forceinline__ float tanh_t(float a, const float2* __restrict__ tbl) {
    float u = fmaf(a, TBL_SCALE, TBL_BIAS);
    u = fminf(fmaxf(u, 0.0f), TBL_MAXU);
    int   i = (int)u;                 // trunc == floor (u >= 0)
    float f = u - (float)i;
    float2 e = tbl[i];
    return fmaf(f, e.y, e.x);
}

#define WARGS const float* __restrict__ W1, const float* __restrict__ b1, \
              const float* __restrict__ W2, const float* __restrict__ b2, \
              const float* __restrict__ W3, const float* __restrict__ b3, \
              const float* __restrict__ W4, const float* __restrict__ b4, \
              const float* __restrict__ W5, const float* __restrict__ b5, \
              const float* __restrict__ W6, const float* __restrict__ b6, \
              const float* __restrict__ Wh, const float* __restrict__ bh
#define WPASS W1,b1,W2,b2,W3,b3,W4,b4,W5,b5,W6,b6,Wh,bh

// Full MLP for one row -> p0 = sigmoid(l0 - l1). All tanh via LDS table.
__device__ __forceinline__ float mlp_p0(float x0, float x1, const float2* __restrict__ tbl, WARGS) {
    float h1[8];
#pragma unroll
    for (int j = 0; j < 8; ++j)
        h1[j] = tanh_t(fmaf(x1, W1[2*j+1], fmaf(x0, W1[2*j], b1[j])), tbl);
    float h2[8];
#pragma unroll
    for (int j = 0; j < 8; ++j) {
        float a = b2[j];
#pragma unroll
        for (int k = 0; k < 8; ++k) a = fmaf(h1[k], W2[8*j+k], a);
        h2[j] = tanh_t(a, tbl);
    }
    float h3[6];
#pragma unroll
    for (int j = 0; j < 6; ++j) {
        float a = b3[j];
#pragma unroll
        for (int k = 0; k < 8; ++k) a = fmaf(h2[k], W3[8*j+k], a);
        h3[j] = tanh_t(a, tbl);
    }
    float h4[4];
#pragma unroll
    for (int j = 0; j < 4; ++j) {
        float a = b4[j];
#pragma unroll
        for (int k = 0; k < 6; ++k) a = fmaf(h3[k], W4[6*j+k], a);
        h4[j] = tanh_t(a, tbl);
    }
    float h5[3];
#pragma unroll
    for (int j = 0; j < 3; ++j) {
        float a = b5[j];
#pragma unroll
        for (int k = 0; k < 4; ++k) a = fmaf(h4[k], W5[4*j+k], a);
        h5[j] = tanh_t(a, tbl);
    }
    float h6[3];
#pragma unroll
    for (int j = 0; j < 3; ++j) {
        float a = b6[j];
#pragma unroll
        for (int k = 0; k < 3; ++k) a = fmaf(h5[k], W6[3*j+k], a);
        h6[j] = tanh_t(a, tbl);
    }
    float d = bh[0] - bh[1];
#pragma unroll
    for (int j = 0; j < 3; ++j) d = fmaf(h6[j], Wh[j] - Wh[3+j], d);
    return __fdividef(1.0f, 1.0f + __expf(-d));   // 1 sigmoid/row: keep exact
}

// Pass 1: p0 per row -> store + reduce (sum, sumsq).
__global__ __launch_bounds__(THREADS) void k1_probs(
    const float* __restrict__ x, const float2* __restrict__ gtbl, WARGS,
    float* __restrict__ p0out, double* __restrict__ acc)
{
    __shared__ float2 tbl[TBL_N];                 // 32 KB
#pragma unroll
    for (int i = threadIdx.x; i < TBL_N; i += THREADS) tbl[i] = gtbl[i];
    __syncthreads();

    const int t = blockIdx.x * THREADS + threadIdx.x;
    float s = 0.0f, q = 0.0f;
#pragma unroll
    for (int it = 0; it < 8; ++it) {
        const int rp = it * K1_TOT + t;           // float4 of x = rows 2rp, 2rp+1
        float4 xv = reinterpret_cast<const float4*>(x)[rp];
        float pa = mlp_p0(xv.x, xv.y, tbl, WPASS);
        float pb = mlp_p0(xv.z, xv.w, tbl, WPASS);
        reinterpret_cast<float2*>(p0out)[rp] = make_float2(pa, pb);
        s += pa + pb;
        q += fmaf(pa, pa, pb * pb);
    }
#pragma unroll
    for (int off = 32; off > 0; off >>= 1) {
        s += __shfl_down(s, off);
        q += __shfl_down(q, off);
    }
    __shared__ float ls[THREADS / 64], lq[THREADS / 64];
    const int lane = threadIdx.x & 63, wv = threadIdx.x >> 6;
    if (lane == 0) { ls[wv] = s; lq[wv] = q; }
    __syncthreads();
    if (threadIdx.x == 0) {
        float S = ls[0] + ls[1] + ls[2] + ls[3];
        float Q = lq[0] + lq[1] + lq[2] + lq[3];
        atomicAdd(&acc[0], (double)S);
        atomicAdd(&acc[1], (double)Q);
    }
}

// Tiny: fold f64 accumulators into 4 float BN coefficients.
__global__ void k_stats(const double* __restrict__ acc,
                        const float* __restrict__ gamma, const float* __restrict__ beta,
                        float* __restrict__ coef)
{
    if (threadIdx.x == 0) {
        double S = acc[0], Q = acc[1];
        double md   = S / (double)ROWS;
        double vard = (Q - S * md) / (double)ROWS;
        float  m    = (float)md;
        float  inv  = rsqrtf((float)vard + EPSF);
        float  a0 = inv * gamma[0], a1 = inv * gamma[1];
        coef[0] = a0;                    // out0 =  p*a0 + c0
        coef[1] = beta[0] - m * a0;
        coef[2] = a1;                    // out1 = -p*a1 + c1
        coef[3] = beta[1] + m * a1;
    }
}

// Pass 2: normalize (no f64, coefficients precomputed).
__global__ __launch_bounds__(THREADS) void k2_norm(
    const float* __restrict__ p0in, const float* __restrict__ coef,
    float* __restrict__ out)
{
    const float a0 = coef[0], c0 = coef[1], a1 = coef[2], c1 = coef[3];
    const int t = blockIdx.x * THREADS + threadIdx.x;
#pragma unroll
    for (int it = 0; it < 4; ++it) {
        const int idx = it * K2_TOT + t;
        float2 p = reinterpret_cast<const float2*>(p0in)[idx];
        float4 o;
        o.x = fmaf( p.x, a0, c0);
        o.y = fmaf(-p.x, a1, c1);
        o.z = fmaf( p.y, a0, c0);
        o.w = fmaf(-p.y, a1, c1);
        reinterpret_cast<float4*>(out)[idx] = o;
    }
}

// Fallback pass 2 (no ws for p0): recompute via table.
__global__ __launch_bounds__(THREADS) void k2_recompute(
    const float* __restrict__ x, const float2* __restrict__ gtbl, WARGS,
    const float* __restrict__ coef, float* __restrict__ out)
{
    __shared__ float2 tbl[TBL_N];
#pragma unroll
    for (int i = threadIdx.x; i < TBL_N; i += THREADS) tbl[i] = gtbl[i];
    __syncthreads();
    const float a0 = coef[0], c0 = coef[1], a1 = coef[2], c1 = coef[3];
    const int t = blockIdx.x * THREADS + threadIdx.x;
#pragma unroll
    for (int it = 0; it < 8; ++it) {
        const int rp = it * K1_TOT + t;
        float4 xv = reinterpret_cast<const float4*>(x)[rp];
        float pa = mlp_p0(xv.x, xv.y, tbl, WPASS);
        float pb = mlp_p0(xv.z, xv.w, tbl, WPASS);
        float4 o;
        o.x = fmaf( pa, a0, c0);
        o.y = fmaf(-pa, a1, c1);
        o.z = fmaf( pb, a0, c0);
        o.w = fmaf(-pb, a1, c1);
        reinterpret_cast<float4*>(out)[rp] = o;
    }
}

extern "C" void kernel_launch(void* const* d_in, const int* in_sizes, int n_in,
                              void* d_out, int out_size, void* d_ws, size_t ws_size,
                              hipStream_t stream) {
    const float* x  = (const float*)d_in[0];
    const float* W1 = (const float*)d_in[1];
    const float* b1 = (const float*)d_in[2];
    const float* W2 = (const float*)d_in[3];
    const float* b2 = (const float*)d_in[4];
    const float* W3 = (const float*)d_in[5];
    const float* b3 = (const float*)d_in[6];
    const float* W4 = (const float*)d_in[7];
    const float* b4 = (const float*)d_in[8];
    const float* W5 = (const float*)d_in[9];
    const float* b5 = (const float*)d_in[10];
    const float* W6 = (const float*)d_in[11];
    const float* b6 = (const float*)d_in[12];
    const float* Wh = (const float*)d_in[13];
    const float* bh = (const float*)d_in[14];
    const float* gamma = (const float*)d_in[15];
    const float* beta  = (const float*)d_in[16];
    float* out = (float*)d_out;

    // ws layout: [0,16) f64 acc | [16,32) f32 coef | [64, 64+32KB) table | [40960, +16MB) p0
    double* acc  = (double*)d_ws;
    float*  coef = (float*)((char*)d_ws + 16);
    float2* gtbl = (float2*)((char*)d_ws + 64);
    float*  p0   = (float*)((char*)d_ws + 40960);

    hipMemsetAsync(d_ws, 0, 16, stream);   // zero acc
    k0_build<<<(TBL_N + THREADS - 1) / THREADS, THREADS, 0, stream>>>(gtbl);

    const size_t need = 40960 + (size_t)ROWS * sizeof(float);
    if (ws_size >= need) {
        k1_probs<<<K1_BLOCKS, THREADS, 0, stream>>>(x, gtbl, WPASS, p0, acc);
        k_stats<<<1, 64, 0, stream>>>(acc, gamma, beta, coef);
        k2_norm<<<K2_BLOCKS, THREADS, 0, stream>>>(p0, coef, out);
    } else {
        k1_probs<<<K1_BLOCKS, THREADS, 0, stream>>>(x, gtbl, WPASS, p0, acc);  // p0 store may be OOB-safe only on ws path
        k_stats<<<1, 64, 0, stream>>>(acc, gamma, beta, coef);
        k2_recompute<<<K1_BLOCKS, THREADS, 0, stream>>>(x, gtbl, WPASS, coef, out);
    }
}

// Round 4
// 179.819 us; speedup vs baseline: 1.2201x; 1.0600x over previous
//
#include <hip/hip_runtime.h>

#define EPSF 1e-5f
constexpr int ROWS      = 4194304;             // B
constexpr int THREADS   = 256;
constexpr int K1_BLOCKS = 2048;                // 8 rows/thread
constexpr int K2_BLOCKS = 2048;
constexpr int K1_TOT    = K1_BLOCKS * THREADS;
constexpr int K2_TOT    = K2_BLOCKS * THREADS;

// ---- tanh lookup: 1024+1 float values in LDS, linear interp, range [-8,8] ----
// interp err <= h^2/8 * max|tanh''| = (0.015625^2/8)*0.77 = 2.4e-5
constexpr int   TBL_N     = 1024;
constexpr float TBL_R     = 8.0f;
constexpr float TBL_STEP  = 2.0f * TBL_R / TBL_N;   // 0.015625
constexpr float TBL_SCALE = TBL_N / (2.0f * TBL_R); // 64
constexpr float TBL_BIAS  = TBL_N * 0.5f;           // 512
constexpr float TBL_MAXU  = 1023.999f;

__device__ __forceinline__ float exact_tanh(float v) {
    float e = __expf(2.0f * v);
    return 1.0f - __fdividef(2.0f, e + 1.0f);
}

// ~7 VALU + 1 ds_read2_b32
__device__ __forceinline__ float tanh_t(float a, const float* __restrict__ tv) {
    float u = fmaf(a, TBL_SCALE, TBL_BIAS);
    u = fminf(fmaxf(u, 0.0f), TBL_MAXU);
    int   i = (int)u;
    float f = u - (float)i;
    float v0 = tv[i];
    float v1 = tv[i + 1];
    return fmaf(f, v1 - v0, v0);
}

#define WARGS const float* __restrict__ W1, const float* __restrict__ b1, \
              const float* __restrict__ W2, const float* __restrict__ b2, \
              const float* __restrict__ W3, const float* __restrict__ b3, \
              const float* __restrict__ W4, const float* __restrict__ b4, \
              const float* __restrict__ W5, const float* __restrict__ b5, \
              const float* __restrict__ W6, const float* __restrict__ b6, \
              const float* __restrict__ Wh, const float* __restrict__ bh
#define WPASS W1,b1,W2,b2,W3,b3,W4,b4,W5,b5,W6,b6,Wh,bh

__device__ __forceinline__ float mlp_p0(float x0, float x1, const float* __restrict__ tv, WARGS) {
    float h1[8];
#pragma unroll
    for (int j = 0; j < 8; ++j)
        h1[j] = tanh_t(fmaf(x1, W1[2*j+1], fmaf(x0, W1[2*j], b1[j])), tv);
    float h2[8];
#pragma unroll
    for (int j = 0; j < 8; ++j) {
        float a = b2[j];
#pragma unroll
        for (int k = 0; k < 8; ++k) a = fmaf(h1[k], W2[8*j+k], a);
        h2[j] = tanh_t(a, tv);
    }
    float h3[6];
#pragma unroll
    for (int j = 0; j < 6; ++j) {
        float a = b3[j];
#pragma unroll
        for (int k = 0; k < 8; ++k) a = fmaf(h2[k], W3[8*j+k], a);
        h3[j] = tanh_t(a, tv);
    }
    float h4[4];
#pragma unroll
    for (int j = 0; j < 4; ++j) {
        float a = b4[j];
#pragma unroll
        for (int k = 0; k < 6; ++k) a = fmaf(h3[k], W4[6*j+k], a);
        h4[j] = tanh_t(a, tv);
    }
    float h5[3];
#pragma unroll
    for (int j = 0; j < 3; ++j) {
        float a = b5[j];
#pragma unroll
        for (int k = 0; k < 4; ++k) a = fmaf(h4[k], W5[4*j+k], a);
        h5[j] = tanh_t(a, tv);
    }
    float h6[3];
#pragma unroll
    for (int j = 0; j < 3; ++j) {
        float a = b6[j];
#pragma unroll
        for (int k = 0; k < 3; ++k) a = fmaf(h5[k], W6[3*j+k], a);
        h6[j] = tanh_t(a, tv);
    }
    float d = bh[0] - bh[1];
#pragma unroll
    for (int j = 0; j < 3; ++j) d = fmaf(h6[j], Wh[j] - Wh[3+j], d);
    return __fdividef(1.0f, 1.0f + __expf(-d));   // one exact sigmoid per row
}

// Pass 1: build tanh table in LDS, compute p0 per row, store p0,
// write per-block (sum, sumsq) partial — no atomics, no pre-zeroing needed.
template <bool STORE>
__global__ __launch_bounds__(THREADS) void k1_probs(
    const float* __restrict__ x, WARGS,
    float* __restrict__ p0out, float2* __restrict__ partial)
{
    __shared__ float tv[TBL_N + 1];               // 4.1 KB
    for (int i = threadIdx.x; i <= TBL_N; i += THREADS)
        tv[i] = exact_tanh(-TBL_R + (float)i * TBL_STEP);
    __syncthreads();

    const int t = blockIdx.x * THREADS + threadIdx.x;
    float s = 0.0f, q = 0.0f;
#pragma unroll
    for (int it = 0; it < 4; ++it) {
        const int rp = it * K1_TOT + t;           // float4 of x = rows 2rp, 2rp+1
        float4 xv = reinterpret_cast<const float4*>(x)[rp];
        float pa = mlp_p0(xv.x, xv.y, tv, WPASS);
        float pb = mlp_p0(xv.z, xv.w, tv, WPASS);
        if (STORE)
            reinterpret_cast<float2*>(p0out)[rp] = make_float2(pa, pb);
        s += pa + pb;
        q += fmaf(pa, pa, pb * pb);
    }
#pragma unroll
    for (int off = 32; off > 0; off >>= 1) {
        s += __shfl_down(s, off);
        q += __shfl_down(q, off);
    }
    __shared__ float ls[THREADS / 64], lq[THREADS / 64];
    const int lane = threadIdx.x & 63, wv = threadIdx.x >> 6;
    if (lane == 0) { ls[wv] = s; lq[wv] = q; }
    __syncthreads();
    if (threadIdx.x == 0)
        partial[blockIdx.x] = make_float2(ls[0] + ls[1] + ls[2] + ls[3],
                                          lq[0] + lq[1] + lq[2] + lq[3]);
}

// Shared helper: reduce the 2048 block partials (redundantly per block) -> 4 coefs in LDS.
__device__ __forceinline__ void reduce_coef(
    const float2* __restrict__ partial,
    const float* __restrict__ gamma, const float* __restrict__ beta,
    float* __restrict__ cs /*__shared__ float[4]*/)
{
    float s = 0.0f, q = 0.0f;
#pragma unroll
    for (int i = threadIdx.x; i < K1_BLOCKS; i += THREADS) {
        float2 v = partial[i];
        s += v.x; q += v.y;
    }
#pragma unroll
    for (int off = 32; off > 0; off >>= 1) {
        s += __shfl_down(s, off);
        q += __shfl_down(q, off);
    }
    __shared__ float ls[THREADS / 64], lq[THREADS / 64];
    const int lane = threadIdx.x & 63, wv = threadIdx.x >> 6;
    if (lane == 0) { ls[wv] = s; lq[wv] = q; }
    __syncthreads();
    if (threadIdx.x == 0) {
        double S = (double)ls[0] + ls[1] + ls[2] + ls[3];
        double Q = (double)lq[0] + lq[1] + lq[2] + lq[3];
        double md   = S / (double)ROWS;
        double vard = (Q - S * md) / (double)ROWS;
        float  m    = (float)md;
        float  inv  = rsqrtf((float)vard + EPSF);
        float  a0 = inv * gamma[0], a1 = inv * gamma[1];
        cs[0] = a0;                  // out0 =  p*a0 + c0
        cs[1] = beta[0] - m * a0;
        cs[2] = a1;                  // out1 = -p*a1 + c1
        cs[3] = beta[1] + m * a1;
    }
    __syncthreads();
}

// Pass 2: reduce partials (L2-resident, redundant per block) then normalize.
__global__ __launch_bounds__(THREADS) void k2_norm(
    const float* __restrict__ p0in, const float2* __restrict__ partial,
    const float* __restrict__ gamma, const float* __restrict__ beta,
    float* __restrict__ out)
{
    __shared__ float cs[4];
    reduce_coef(partial, gamma, beta, cs);
    const float a0 = cs[0], c0 = cs[1], a1 = cs[2], c1 = cs[3];
    const int t = blockIdx.x * THREADS + threadIdx.x;
#pragma unroll
    for (int it = 0; it < 4; ++it) {
        const int idx = it * K2_TOT + t;
        float2 p = reinterpret_cast<const float2*>(p0in)[idx];
        float4 o;
        o.x = fmaf( p.x, a0, c0);
        o.y = fmaf(-p.x, a1, c1);
        o.z = fmaf( p.y, a0, c0);
        o.w = fmaf(-p.y, a1, c1);
        reinterpret_cast<float4*>(out)[idx] = o;
    }
}

// Fallback pass 2 (no ws for p0): recompute via in-LDS table.
__global__ __launch_bounds__(THREADS) void k2_recompute(
    const float* __restrict__ x, WARGS, const float2* __restrict__ partial,
    const float* __restrict__ gamma, const float* __restrict__ beta,
    float* __restrict__ out)
{
    __shared__ float cs[4];
    reduce_coef(partial, gamma, beta, cs);
    __shared__ float tv[TBL_N + 1];
    for (int i = threadIdx.x; i <= TBL_N; i += THREADS)
        tv[i] = exact_tanh(-TBL_R + (float)i * TBL_STEP);
    __syncthreads();
    const float a0 = cs[0], c0 = cs[1], a1 = cs[2], c1 = cs[3];
    const int t = blockIdx.x * THREADS + threadIdx.x;
#pragma unroll
    for (int it = 0; it < 4; ++it) {
        const int rp = it * K1_TOT + t;
        float4 xv = reinterpret_cast<const float4*>(x)[rp];
        float pa = mlp_p0(xv.x, xv.y, tv, WPASS);
        float pb = mlp_p0(xv.z, xv.w, tv, WPASS);
        float4 o;
        o.x = fmaf( pa, a0, c0);
        o.y = fmaf(-pa, a1, c1);
        o.z = fmaf( pb, a0, c0);
        o.w = fmaf(-pb, a1, c1);
        reinterpret_cast<float4*>(out)[rp] = o;
    }
}

extern "C" void kernel_launch(void* const* d_in, const int* in_sizes, int n_in,
                              void* d_out, int out_size, void* d_ws, size_t ws_size,
                              hipStream_t stream) {
    const float* x  = (const float*)d_in[0];
    const float* W1 = (const float*)d_in[1];
    const float* b1 = (const float*)d_in[2];
    const float* W2 = (const float*)d_in[3];
    const float* b2 = (const float*)d_in[4];
    const float* W3 = (const float*)d_in[5];
    const float* b3 = (const float*)d_in[6];
    const float* W4 = (const float*)d_in[7];
    const float* b4 = (const float*)d_in[8];
    const float* W5 = (const float*)d_in[9];
    const float* b5 = (const float*)d_in[10];
    const float* W6 = (const float*)d_in[11];
    const float* b6 = (const float*)d_in[12];
    const float* Wh = (const float*)d_in[13];
    const float* bh = (const float*)d_in[14];
    const float* gamma = (const float*)d_in[15];
    const float* beta  = (const float*)d_in[16];
    float* out = (float*)d_out;

    // ws layout: [0, 16KB) block partials | [16KB, +16MB) p0
    float2* partial = (float2*)d_ws;
    float*  p0      = (float*)((char*)d_ws + 16384);

    const size_t need = 16384 + (size_t)ROWS * sizeof(float);
    if (ws_size >= need) {
        k1_probs<true><<<K1_BLOCKS, THREADS, 0, stream>>>(x, WPASS, p0, partial);
        k2_norm<<<K2_BLOCKS, THREADS, 0, stream>>>(p0, partial, gamma, beta, out);
    } else {
        k1_probs<false><<<K1_BLOCKS, THREADS, 0, stream>>>(x, WPASS, p0, partial);
        k2_recompute<<<K1_BLOCKS, THREADS, 0, stream>>>(x, WPASS, partial, gamma, beta, out);
    }
}